// Round 12
// baseline (210.286 us; speedup 1.0000x reference)
//
#include <hip/hip_runtime.h>

// KPMiniMod round 12 (= round 11 measurement round, resubmitted after broker
// timeout). Kernels byte-identical to round 10. kp_gather_v4 launched 5x
// (idempotent) to split the blind mlp/kp sum: kp = (total - 120.2)/4.

#define MQ 32000

typedef unsigned short u16;
typedef unsigned int   u32;
typedef __attribute__((ext_vector_type(8))) short bf16x8;
typedef __attribute__((ext_vector_type(4))) float f32x4;

__device__ __forceinline__ float rlf(float v, int l) {
    return __int_as_float(__builtin_amdgcn_readlane(__float_as_int(v), l));
}
__device__ __forceinline__ int rli(int v, int l) {
    return __builtin_amdgcn_readlane(v, l);
}
__device__ __forceinline__ u16 f2bf(float x) {   // f32 -> bf16 RTNE
    u32 u = __float_as_uint(x);
    return (u16)((u + 0x7FFFu + ((u >> 16) & 1u)) >> 16);
}
__device__ __forceinline__ float bf2f(u16 b) {
    return __uint_as_float(((u32)b) << 16);
}

// ---------------------------------------------------------------- kernel 0
__global__ void prep_weights(const float* __restrict__ w1,
                             const float* __restrict__ w2,
                             u16* __restrict__ w1p,   // 4096 u16
                             u16* __restrict__ w2p)   // 8192 u16 (cols 120.. zero)
{
    const int tid = threadIdx.x;
    for (int i = tid; i < 64 * 64; i += 256) {
        const int k = i >> 6, j = i & 63;
        const int dst = (((k >> 5) * 4 + ((k >> 3) & 3)) * 4 + (j >> 4)) * 128
                        + (j & 15) * 8 + (k & 7);
        w1p[dst] = f2bf(w1[i]);
    }
    for (int i = tid; i < 64 * 128; i += 256) {
        const int k = i >> 7, j = i & 127;
        const int dst = (((k >> 5) * 4 + ((k >> 3) & 3)) * 8 + (j >> 4)) * 128
                        + (j & 15) * 8 + (k & 7);
        w2p[dst] = (j < 120) ? f2bf(w2[k * 120 + j]) : (u16)0;
    }
}

// ---------------------------------------------------------------- kernel 1
__global__ __launch_bounds__(256, 2)
void mod_mlp_mfma2(const float* __restrict__ s_feats,
                   const u16*   __restrict__ w1p,
                   const float* __restrict__ b1,
                   const u16*   __restrict__ w2p,
                   u16* __restrict__ modw,   // (M,120) bf16, sigmoid applied
                   u16* __restrict__ fb)     // (M,64) bf16 feature table
{
    __shared__ u16 hb[4][16 * 64];  // 8 KB: wave-private H transpose buffers

    const int tid  = threadIdx.x;
    const int lane = tid & 63;
    const int wid  = tid >> 6;
    const int jj   = lane & 15;
    const int rbg  = lane >> 4;          // 0..3
    const int rb   = rbg * 8;
    const int rowC = rbg * 4;

    const int t  = blockIdx.x * 4 + wid;   // one tile per wave (2000 tiles)
    const int m0 = t * 16;

    // ---- A fragments: rows m0+jj ----
    const float* ar = s_feats + (size_t)(m0 + jj) * 64 + rb;
    float4 v0 = *(const float4*)(ar);
    float4 v1 = *(const float4*)(ar + 4);
    float4 v2 = *(const float4*)(ar + 32);
    float4 v3 = *(const float4*)(ar + 36);
    bf16x8 a0, a1;
    a0[0] = (short)f2bf(v0.x); a0[1] = (short)f2bf(v0.y);
    a0[2] = (short)f2bf(v0.z); a0[3] = (short)f2bf(v0.w);
    a0[4] = (short)f2bf(v1.x); a0[5] = (short)f2bf(v1.y);
    a0[6] = (short)f2bf(v1.z); a0[7] = (short)f2bf(v1.w);
    a1[0] = (short)f2bf(v2.x); a1[1] = (short)f2bf(v2.y);
    a1[2] = (short)f2bf(v2.z); a1[3] = (short)f2bf(v2.w);
    a1[4] = (short)f2bf(v3.x); a1[5] = (short)f2bf(v3.y);
    a1[6] = (short)f2bf(v3.z); a1[7] = (short)f2bf(v3.w);

    *(bf16x8*)(fb + (size_t)(m0 + jj) * 64 + rb)      = a0;
    *(bf16x8*)(fb + (size_t)(m0 + jj) * 64 + 32 + rb) = a1;

    float b1v[4];
    #pragma unroll
    for (int nt = 0; nt < 4; ++nt) b1v[nt] = b1[nt * 16 + jj];

    // ---- GEMM1: H = leaky(F @ W1 + b1), fragments jit from L2 ----
    f32x4 acc[4];
    #pragma unroll
    for (int nt = 0; nt < 4; ++nt) {
        const bf16x8 f0 = *(const bf16x8*)(w1p + ((0 * 4 + rbg) * 4 + nt) * 128 + jj * 8);
        const bf16x8 f1 = *(const bf16x8*)(w1p + ((1 * 4 + rbg) * 4 + nt) * 128 + jj * 8);
        f32x4 z = {0.f, 0.f, 0.f, 0.f};
        z = __builtin_amdgcn_mfma_f32_16x16x32_bf16(a0, f0, z, 0, 0, 0);
        acc[nt] = __builtin_amdgcn_mfma_f32_16x16x32_bf16(a1, f1, z, 0, 0, 0);
    }
    u16* hrow = &hb[wid][0];
    #pragma unroll
    for (int nt = 0; nt < 4; ++nt) {
        #pragma unroll
        for (int r = 0; r < 4; ++r) {
            float h = acc[nt][r] + b1v[nt];
            h = (h >= 0.f) ? h : 0.1f * h;
            hrow[(rowC + r) * 64 + nt * 16 + jj] = f2bf(h);
        }
    }
    const bf16x8 ha0 = *(bf16x8*)(hrow + jj * 64 + rb);
    const bf16x8 ha1 = *(bf16x8*)(hrow + jj * 64 + 32 + rb);

    // ---- GEMM2 + sigmoid + bf16 store ----
    #pragma unroll
    for (int nt = 0; nt < 8; ++nt) {
        const bf16x8 g0 = *(const bf16x8*)(w2p + ((0 * 4 + rbg) * 8 + nt) * 128 + jj * 8);
        const bf16x8 g1 = *(const bf16x8*)(w2p + ((1 * 4 + rbg) * 8 + nt) * 128 + jj * 8);
        f32x4 z = {0.f, 0.f, 0.f, 0.f};
        z = __builtin_amdgcn_mfma_f32_16x16x32_bf16(ha0, g0, z, 0, 0, 0);
        f32x4 c2 = __builtin_amdgcn_mfma_f32_16x16x32_bf16(ha1, g1, z, 0, 0, 0);
        const int j = nt * 16 + jj;
        if (j < 120) {
            #pragma unroll
            for (int r = 0; r < 4; ++r)
                modw[(size_t)(m0 + rowC + r) * 120 + j] =
                    f2bf(1.f / (1.f + __expf(-c2[r])));
        }
    }
}

// ---------------------------------------------------------------- kernel 2
__global__ __launch_bounds__(256, 4)
void kp_gather_v4(const float* __restrict__ q_pts,
                  const float* __restrict__ s_pts,
                  const u16*   __restrict__ fb,
                  const int*   __restrict__ neighb_inds,
                  const float* __restrict__ kpts,
                  const float* __restrict__ weights,
                  const u32*   __restrict__ modw32,  // (M,120) bf16 as u32 words
                  float* __restrict__ out)
{
    __shared__ float wt_lds[15 * 64];
    const int tid = threadIdx.x;
    if (tid < 240) ((float4*)wt_lds)[tid] = ((const float4*)weights)[tid];
    __syncthreads();

    const int lane = tid & 63;
    const int wid  = tid >> 6;
    const int pair = blockIdx.x * 4 + wid;   // 16000 pairs exactly
    const int m0 = pair * 2;

    // ---- coalesced index load: lane = q*32 + h ----
    const int ind = __builtin_nontemporal_load(&neighb_inds[(size_t)m0 * 32 + lane]);

    // ---- issue 8 row-gathers immediately ----
    const int cdiv = lane & 7;
    const int hl   = lane >> 3;
    bf16x8 fv[2][4];
    #pragma unroll
    for (int qq = 0; qq < 2; ++qq)
        #pragma unroll
        for (int cc = 0; cc < 4; ++cc) {
            const int ih = __shfl(ind, qq * 32 + cc * 8 + hl);
            fv[qq][cc] = *(const bf16x8*)(fb + (size_t)(u32)ih * 64 + cdiv * 8);
        }

    // ---- modulation words (bf16 pairs): lane<60 holds slots 2*lane,2*lane+1 ----
    const u32 W0 = (lane < 60) ? __builtin_nontemporal_load(&modw32[(size_t)m0 * 60 + lane]) : 0u;
    const u32 W1 = (lane < 60) ? __builtin_nontemporal_load(&modw32[(size_t)(m0 + 1) * 60 + lane]) : 0u;

    // ---- influence (under gather latency): lane = q*32 + h ----
    const int q = lane >> 5;
    const int m = m0 + q;
    const float qx = q_pts[m * 3 + 0];
    const float qy = q_pts[m * 3 + 1];
    const float qz = q_pts[m * 3 + 2];
    const float px = s_pts[(size_t)ind * 3 + 0] - qx;
    const float py = s_pts[(size_t)ind * 3 + 1] - qy;
    const float pz = s_pts[(size_t)ind * 3 + 2] - qz;
    float best = 1e30f; int bk = 0;
    #pragma unroll
    for (int k = 0; k < 15; ++k) {            // kpts -> uniform SGPR loads
        float ex = px - kpts[k * 3 + 0];
        float ey = py - kpts[k * 3 + 1];
        float ez = pz - kpts[k * 3 + 2];
        float d2 = fmaf(ex, ex, fmaf(ey, ey, ez * ez));
        if (d2 < best) { best = d2; bk = k; } // strict < = first-min (argmin rule)
    }
    const float infl = fmaxf(0.f, 1.f - sqrtf(best));   // SIGMA = 1

    // ---- consume ----
    float acc[2][8];
    #pragma unroll
    for (int qq = 0; qq < 2; ++qq)
        #pragma unroll
        for (int e = 0; e < 8; ++e) acc[qq][e] = 0.f;

    #pragma unroll
    for (int qq = 0; qq < 2; ++qq) {
        #pragma unroll
        for (int cc = 0; cc < 4; ++cc) {
            const int idx = qq * 32 + cc * 8 + hl;
            const int kh  = __shfl(bk, idx);
            const float fl = __shfl(infl, idx);
            const int j = kh * 8 + cdiv;
            const u32 w32 = (u32)__shfl((int)(qq ? W1 : W0), j >> 1);
            const u16 hbf = (j & 1) ? (u16)(w32 >> 16) : (u16)(w32 & 0xffffu);
            const float w = bf2f(hbf) * fl;
            const float4 wa = *(const float4*)&wt_lds[kh * 64 + cdiv * 8];
            const float4 wb = *(const float4*)&wt_lds[kh * 64 + cdiv * 8 + 4];
            const bf16x8 f8 = fv[qq][cc];
            acc[qq][0] = fmaf(bf2f((u16)f8[0]), wa.x * w, acc[qq][0]);
            acc[qq][1] = fmaf(bf2f((u16)f8[1]), wa.y * w, acc[qq][1]);
            acc[qq][2] = fmaf(bf2f((u16)f8[2]), wa.z * w, acc[qq][2]);
            acc[qq][3] = fmaf(bf2f((u16)f8[3]), wa.w * w, acc[qq][3]);
            acc[qq][4] = fmaf(bf2f((u16)f8[4]), wb.x * w, acc[qq][4]);
            acc[qq][5] = fmaf(bf2f((u16)f8[5]), wb.y * w, acc[qq][5]);
            acc[qq][6] = fmaf(bf2f((u16)f8[6]), wb.z * w, acc[qq][6]);
            acc[qq][7] = fmaf(bf2f((u16)f8[7]), wb.w * w, acc[qq][7]);
        }
    }

    // ---- butterfly reduce over hl (lane bits 3..5) ----
    #pragma unroll
    for (int step = 8; step <= 32; step <<= 1)
        #pragma unroll
        for (int qq = 0; qq < 2; ++qq)
            #pragma unroll
            for (int e = 0; e < 8; ++e)
                acc[qq][e] += __shfl_xor(acc[qq][e], step);

    if (hl == 0) {
        #pragma unroll
        for (int qq = 0; qq < 2; ++qq) {
            f32x4 o0 = {acc[qq][0], acc[qq][1], acc[qq][2], acc[qq][3]};
            f32x4 o1 = {acc[qq][4], acc[qq][5], acc[qq][6], acc[qq][7]};
            float* dst = out + (size_t)(m0 + qq) * 64 + cdiv * 8;
            __builtin_nontemporal_store(o0, (f32x4*)dst);
            __builtin_nontemporal_store(o1, (f32x4*)(dst + 4));
        }
    }
}

// ------------------- fallback tier: proven f32 path -------------------
__global__ __launch_bounds__(256, 3)
void mod_mlp(const float* __restrict__ s_feats,
             const float* __restrict__ w1,
             const float* __restrict__ b1,
             const float* __restrict__ w2,
             float* __restrict__ modw)
{
    __shared__ float w1_lds[64 * 64];
    __shared__ float w2_lds[64 * 120 + 8];

    const int tid = threadIdx.x;
    {
        const float4* s1 = (const float4*)w1;
        float4* d1 = (float4*)w1_lds;
        #pragma unroll
        for (int i = 0; i < 4; ++i) d1[tid + 256 * i] = s1[tid + 256 * i];
        const float4* s2 = (const float4*)w2;
        float4* d2 = (float4*)w2_lds;
        for (int i = tid; i < (64 * 120) / 4; i += 256) d2[i] = s2[i];
        if (tid < 8) w2_lds[64 * 120 + tid] = 0.f;
    }
    __syncthreads();

    const int lane = tid & 63;
    const int wid  = tid >> 6;
    const int c    = lane;
    const int nwaves = gridDim.x * 4;
    const int gwave  = blockIdx.x * 4 + wid;
    const float b1v = b1[c];
    const int cB = 64 + ((c < 56) ? c : 55);

    for (int pair = gwave; pair * 2 < MQ; pair += nwaves) {
        const int m0 = pair * 2;
        float f0 = s_feats[(size_t)m0 * 64 + c];
        float f1 = s_feats[(size_t)(m0 + 1) * 64 + c];
        float h0a = b1v, h0b = 0.f, h1a = b1v, h1b = 0.f;
        #pragma unroll
        for (int i = 0; i < 64; i += 2) {
            float wa = w1_lds[i * 64 + c];
            float wb = w1_lds[(i + 1) * 64 + c];
            h0a = fmaf(rlf(f0, i), wa, h0a);
            h0b = fmaf(rlf(f0, i + 1), wb, h0b);
            h1a = fmaf(rlf(f1, i), wa, h1a);
            h1b = fmaf(rlf(f1, i + 1), wb, h1b);
        }
        float h0 = h0a + h0b, h1 = h1a + h1b;
        h0 = (h0 >= 0.f) ? h0 : 0.1f * h0;
        h1 = (h1 >= 0.f) ? h1 : 0.1f * h1;
        float a00 = 0.f, a01 = 0.f, a10 = 0.f, a11 = 0.f;
        #pragma unroll
        for (int i = 0; i < 64; ++i) {
            float wA = w2_lds[i * 120 + c];
            float wB = w2_lds[i * 120 + cB];
            float s0 = rlf(h0, i);
            float s1 = rlf(h1, i);
            a00 = fmaf(s0, wA, a00);
            a01 = fmaf(s0, wB, a01);
            a10 = fmaf(s1, wA, a10);
            a11 = fmaf(s1, wB, a11);
        }
        modw[(size_t)m0 * 120 + c]       = 1.f / (1.f + __expf(-a00));
        modw[(size_t)(m0 + 1) * 120 + c] = 1.f / (1.f + __expf(-a10));
        if (c < 56) {
            modw[(size_t)m0 * 120 + 64 + c]       = 1.f / (1.f + __expf(-a01));
            modw[(size_t)(m0 + 1) * 120 + 64 + c] = 1.f / (1.f + __expf(-a11));
        }
    }
}

__global__ __launch_bounds__(256, 4)
void kp_gather(const float* __restrict__ q_pts,
               const float* __restrict__ s_pts,
               const float* __restrict__ s_feats,
               const int*   __restrict__ neighb_inds,
               const float* __restrict__ kpts,
               const float* __restrict__ weights,
               const float* __restrict__ modw,
               float* __restrict__ out)
{
    __shared__ float wt_lds[15 * 64];
    const int tid = threadIdx.x;
    if (tid < 240) ((float4*)wt_lds)[tid] = ((const float4*)weights)[tid];
    __syncthreads();

    const int lane = tid & 63;
    const int wid  = tid >> 6;
    const int c    = lane;
    const int u    = c >> 3;
    const int pair = blockIdx.x * 4 + wid;
    const int m0 = pair * 2;

    const int q = lane >> 5;
    const int m = m0 + q;
    const int ind = neighb_inds[(size_t)m0 * 32 + lane];
    const float qx = q_pts[m * 3 + 0];
    const float qy = q_pts[m * 3 + 1];
    const float qz = q_pts[m * 3 + 2];
    const float px = s_pts[(size_t)ind * 3 + 0] - qx;
    const float py = s_pts[(size_t)ind * 3 + 1] - qy;
    const float pz = s_pts[(size_t)ind * 3 + 2] - qz;
    float best = 1e30f; int bk = 0;
    #pragma unroll
    for (int k = 0; k < 15; ++k) {
        float ex = px - kpts[k * 3 + 0];
        float ey = py - kpts[k * 3 + 1];
        float ez = pz - kpts[k * 3 + 2];
        float d2 = fmaf(ex, ex, fmaf(ey, ey, ez * ez));
        if (d2 < best) { best = d2; bk = k; }
    }
    const float infl = fmaxf(0.f, 1.f - sqrtf(best));
    const int pk = (ind << 4) | bk;

    const size_t mb0 = (size_t)m0 * 120, mb1 = mb0 + 120;
    const float vA0 = modw[mb0 + c];
    const float vB0 = (c < 56) ? modw[mb0 + 64 + c] : 0.f;
    const float vA1 = modw[mb1 + c];
    const float vB1 = (c < 56) ? modw[mb1 + 64 + c] : 0.f;

    float fv0[32], fv1[32];
    #pragma unroll
    for (int h = 0; h < 32; ++h)
        fv0[h] = s_feats[(size_t)(rli(pk, h) >> 4) * 64 + c];
    #pragma unroll
    for (int h = 0; h < 32; ++h)
        fv1[h] = s_feats[(size_t)(rli(pk, 32 + h) >> 4) * 64 + c];

    float p0 = 0.f, p1 = 0.f, p2 = 0.f, p3 = 0.f;
    #pragma unroll
    for (int h = 0; h < 32; h += 4) {
        #pragma unroll
        for (int j = 0; j < 4; ++j) {
            const int s = rli(pk, h + j);
            const int kh = s & 15;
            const float fl = rlf(infl, h + j);
            const float sv = (kh < 8) ? __shfl(vA0, (kh << 3) + u)
                                      : __shfl(vB0, ((kh - 8) << 3) + u);
            const float w = wt_lds[(kh << 6) + c] * sv * fl;
            float& p = (j == 0) ? p0 : (j == 1) ? p1 : (j == 2) ? p2 : p3;
            p = fmaf(fv0[h + j], w, p);
        }
    }
    const float acc0 = (p0 + p1) + (p2 + p3);

    float r0 = 0.f, r1 = 0.f, r2 = 0.f, r3 = 0.f;
    #pragma unroll
    for (int h = 0; h < 32; h += 4) {
        #pragma unroll
        for (int j = 0; j < 4; ++j) {
            const int s = rli(pk, 32 + h + j);
            const int kh = s & 15;
            const float fl = rlf(infl, 32 + h + j);
            const float sv = (kh < 8) ? __shfl(vA1, (kh << 3) + u)
                                      : __shfl(vB1, ((kh - 8) << 3) + u);
            const float w = wt_lds[(kh << 6) + c] * sv * fl;
            float& p = (j == 0) ? r0 : (j == 1) ? r1 : (j == 2) ? r2 : r3;
            p = fmaf(fv1[h + j], w, p);
        }
    }
    const float acc1 = (r0 + r1) + (r2 + r3);

    out[(size_t)m0 * 64 + c]       = acc0;
    out[(size_t)(m0 + 1) * 64 + c] = acc1;
}

extern "C" void kernel_launch(void* const* d_in, const int* in_sizes, int n_in,
                              void* d_out, int out_size, void* d_ws, size_t ws_size,
                              hipStream_t stream) {
    const float* q_pts       = (const float*)d_in[0];
    const float* s_pts       = (const float*)d_in[1];
    const float* s_feats     = (const float*)d_in[2];
    const int*   neighb_inds = (const int*)d_in[3];
    const float* kpts        = (const float*)d_in[4];
    const float* weights     = (const float*)d_in[5];
    const float* w1          = (const float*)d_in[6];
    const float* b1          = (const float*)d_in[7];
    const float* w2          = (const float*)d_in[8];
    float* out = (float*)d_out;

    // ws layout (bf16 path): fb 4.096MB | modw_bf 7.68MB | w1p 8KB | w2p 16KB
    const size_t offFB   = 0;
    const size_t offMODW = (size_t)MQ * 64 * sizeof(u16);
    const size_t offW1P  = offMODW + (size_t)MQ * 120 * sizeof(u16);
    const size_t offW2P  = offW1P + 4096 * sizeof(u16);
    const size_t needBF  = offW2P + 8192 * sizeof(u16);
    const size_t needF32 = (size_t)MQ * 120 * sizeof(float);

    if (ws_size >= needBF) {
        u16* fb    = (u16*)((char*)d_ws + offFB);
        u16* modwb = (u16*)((char*)d_ws + offMODW);
        u16* w1p   = (u16*)((char*)d_ws + offW1P);
        u16* w2p   = (u16*)((char*)d_ws + offW2P);
        prep_weights<<<1, 256, 0, stream>>>(w1, w2, w1p, w2p);
        mod_mlp_mfma2<<<500, 256, 0, stream>>>(s_feats, w1p, b1, w2p, modwb, fb);
        // MEASUREMENT: 5 identical launches (idempotent). kp = (dur - 120.2)/4.
        for (int rep = 0; rep < 5; ++rep)
            kp_gather_v4<<<MQ / 8, 256, 0, stream>>>(q_pts, s_pts, fb, neighb_inds,
                                                     kpts, weights, (const u32*)modwb, out);
    } else if (ws_size >= needF32) {
        float* modw = (float*)d_ws;
        mod_mlp<<<768, 256, 0, stream>>>(s_feats, w1, b1, w2, modw);
        kp_gather<<<MQ / 8, 256, 0, stream>>>(q_pts, s_pts, s_feats, neighb_inds,
                                              kpts, weights, modw, out);
    }
}

// Round 13
// 119.795 us; speedup vs baseline: 1.7554x; 1.7554x over previous
//
#include <hip/hip_runtime.h>

// KPMiniMod round 13: 2-node fusion.
//  Node 1 (fb_build): s_feats -> bf16 fb; blocks 0/1 also build fragment-permuted
//    w1p/w2p. ~12MB traffic.
//  Node 2 (kp_fused): 2000 blocks x 512 thr, 16 queries/block. Wave 0 computes the
//    block's 16-row modulation MLP (MFMA) into LDS; waves 1-7 overlap gather issue
//    + influence; one barrier; consume reads mod from LDS. The separate mlp kernel
//    (+ its node overhead + 15.4MB modw stream) is eliminated — round-12
//    measurement: kp=22.5us, mlp+overhead ~42us unexplained by instruction mix.
//  Fallback: proven f32 two-kernel path if ws too small.

#define MQ 32000

typedef unsigned short u16;
typedef unsigned int   u32;
typedef __attribute__((ext_vector_type(8))) short bf16x8;
typedef __attribute__((ext_vector_type(4))) float f32x4;

__device__ __forceinline__ float rlf(float v, int l) {
    return __int_as_float(__builtin_amdgcn_readlane(__float_as_int(v), l));
}
__device__ __forceinline__ int rli(int v, int l) {
    return __builtin_amdgcn_readlane(v, l);
}
__device__ __forceinline__ u16 f2bf(float x) {   // f32 -> bf16 RTNE
    u32 u = __float_as_uint(x);
    return (u16)((u + 0x7FFFu + ((u >> 16) & 1u)) >> 16);
}
__device__ __forceinline__ float bf2f(u16 b) {
    return __uint_as_float(((u32)b) << 16);
}

// ---------------------------------------------------------------- node 1
// fb = bf16(s_feats); blocks 0/1 additionally build permuted weight tables:
// w1 (k,j) -> w1p[(((k>>5)*4+((k>>3)&3))*4+(j>>4))*128 + (j&15)*8 + (k&7)]
// (w2: nt stride 8) so a lane (jj,rbg) reads fragment [nt][kk] as ONE bf16x8.
__global__ __launch_bounds__(256)
void fb_build(const float* __restrict__ s_feats,
              const float* __restrict__ w1,
              const float* __restrict__ w2,
              u16* __restrict__ fb,
              u16* __restrict__ w1p,   // 4096 u16
              u16* __restrict__ w2p)   // 8192 u16 (cols 120.. zero)
{
    const size_t base = ((size_t)blockIdx.x * 256 + threadIdx.x) * 16;
    if (base < (size_t)MQ * 64) {
        const float4* src = (const float4*)(s_feats + base);
        bf16x8 b0, b1;
        float4 v0 = src[0], v1 = src[1], v2 = src[2], v3 = src[3];
        b0[0] = (short)f2bf(v0.x); b0[1] = (short)f2bf(v0.y);
        b0[2] = (short)f2bf(v0.z); b0[3] = (short)f2bf(v0.w);
        b0[4] = (short)f2bf(v1.x); b0[5] = (short)f2bf(v1.y);
        b0[6] = (short)f2bf(v1.z); b0[7] = (short)f2bf(v1.w);
        b1[0] = (short)f2bf(v2.x); b1[1] = (short)f2bf(v2.y);
        b1[2] = (short)f2bf(v2.z); b1[3] = (short)f2bf(v2.w);
        b1[4] = (short)f2bf(v3.x); b1[5] = (short)f2bf(v3.y);
        b1[6] = (short)f2bf(v3.z); b1[7] = (short)f2bf(v3.w);
        *(bf16x8*)(fb + base)     = b0;
        *(bf16x8*)(fb + base + 8) = b1;
    }
    if (blockIdx.x == 0) {
        for (int i = threadIdx.x; i < 64 * 64; i += 256) {
            const int k = i >> 6, j = i & 63;
            const int dst = (((k >> 5) * 4 + ((k >> 3) & 3)) * 4 + (j >> 4)) * 128
                            + (j & 15) * 8 + (k & 7);
            w1p[dst] = f2bf(w1[i]);
        }
    }
    if (blockIdx.x == 1) {
        for (int i = threadIdx.x; i < 64 * 128; i += 256) {
            const int k = i >> 7, j = i & 127;
            const int dst = (((k >> 5) * 4 + ((k >> 3) & 3)) * 8 + (j >> 4)) * 128
                            + (j & 15) * 8 + (k & 7);
            w2p[dst] = (j < 120) ? f2bf(w2[k * 120 + j]) : (u16)0;
        }
    }
}

// ---------------------------------------------------------------- node 2
// 512 thr = 8 waves; wave w handles pair pb=w (queries m0+2w, m0+2w+1).
// Wave 0 additionally computes the 16-row MLP into mod_lds before the barrier.
__global__ __launch_bounds__(512, 4)
void kp_fused(const float* __restrict__ q_pts,
              const float* __restrict__ s_pts,
              const u16*   __restrict__ fb,
              const int*   __restrict__ neighb_inds,
              const float* __restrict__ kpts,
              const float* __restrict__ weights,
              const u16*   __restrict__ w1p,
              const float* __restrict__ b1,
              const u16*   __restrict__ w2p,
              float* __restrict__ out)
{
    __shared__ float wt_lds[15 * 64];    // 3.75 KB
    __shared__ float mod_lds[16 * 120];  // 7.5  KB (sigmoid f32)
    __shared__ u16  hb[16 * 64];         // 2    KB (wave-0 H transpose)

    const int tid  = threadIdx.x;
    const int lane = tid & 63;
    const int wid  = tid >> 6;           // 0..7
    const int m0   = blockIdx.x * 16;

    if (tid < 240) ((float4*)wt_lds)[tid] = ((const float4*)weights)[tid];

    // ---------------- wave 0: 16-row modulation MLP ----------------
    if (wid == 0) {
        const int jj = lane & 15, rbg = lane >> 4;
        const int rb = rbg * 8, rowC = rbg * 4;
        const u16* arow = fb + (size_t)(m0 + jj) * 64;
        const bf16x8 a0 = *(const bf16x8*)(arow + rb);
        const bf16x8 a1 = *(const bf16x8*)(arow + 32 + rb);
        float b1v[4];
        #pragma unroll
        for (int nt = 0; nt < 4; ++nt) b1v[nt] = b1[nt * 16 + jj];

        f32x4 acc[4];
        #pragma unroll
        for (int nt = 0; nt < 4; ++nt) {
            const bf16x8 f0 = *(const bf16x8*)(w1p + ((0 * 4 + rbg) * 4 + nt) * 128 + jj * 8);
            const bf16x8 f1 = *(const bf16x8*)(w1p + ((1 * 4 + rbg) * 4 + nt) * 128 + jj * 8);
            f32x4 z = {0.f, 0.f, 0.f, 0.f};
            z = __builtin_amdgcn_mfma_f32_16x16x32_bf16(a0, f0, z, 0, 0, 0);
            acc[nt] = __builtin_amdgcn_mfma_f32_16x16x32_bf16(a1, f1, z, 0, 0, 0);
        }
        #pragma unroll
        for (int nt = 0; nt < 4; ++nt) {
            #pragma unroll
            for (int r = 0; r < 4; ++r) {
                float h = acc[nt][r] + b1v[nt];
                h = (h >= 0.f) ? h : 0.1f * h;
                hb[(rowC + r) * 64 + nt * 16 + jj] = f2bf(h);
            }
        }
        const bf16x8 ha0 = *(bf16x8*)(hb + jj * 64 + rb);
        const bf16x8 ha1 = *(bf16x8*)(hb + jj * 64 + 32 + rb);

        #pragma unroll
        for (int nt = 0; nt < 8; ++nt) {
            const bf16x8 g0 = *(const bf16x8*)(w2p + ((0 * 4 + rbg) * 8 + nt) * 128 + jj * 8);
            const bf16x8 g1 = *(const bf16x8*)(w2p + ((1 * 4 + rbg) * 8 + nt) * 128 + jj * 8);
            f32x4 z = {0.f, 0.f, 0.f, 0.f};
            z = __builtin_amdgcn_mfma_f32_16x16x32_bf16(ha0, g0, z, 0, 0, 0);
            f32x4 c2 = __builtin_amdgcn_mfma_f32_16x16x32_bf16(ha1, g1, z, 0, 0, 0);
            const int j = nt * 16 + jj;
            if (j < 120) {
                #pragma unroll
                for (int r = 0; r < 4; ++r)
                    mod_lds[(rowC + r) * 120 + j] = 1.f / (1.f + __expf(-c2[r]));
            }
        }
    }

    // ---------------- all waves: own pair's gathers + influence ----------------
    const int pb  = wid;                 // pair-in-block
    const int m0p = m0 + pb * 2;
    const int ind = __builtin_nontemporal_load(&neighb_inds[(size_t)m0p * 32 + lane]);

    const int cdiv = lane & 7;
    const int hl   = lane >> 3;
    bf16x8 fv[2][4];
    #pragma unroll
    for (int qq = 0; qq < 2; ++qq)
        #pragma unroll
        for (int cc = 0; cc < 4; ++cc) {
            const int ih = __shfl(ind, qq * 32 + cc * 8 + hl);
            fv[qq][cc] = *(const bf16x8*)(fb + (size_t)(u32)ih * 64 + cdiv * 8);
        }

    const int q = lane >> 5;
    const int m = m0p + q;
    const float qx = q_pts[m * 3 + 0];
    const float qy = q_pts[m * 3 + 1];
    const float qz = q_pts[m * 3 + 2];
    const float px = s_pts[(size_t)ind * 3 + 0] - qx;
    const float py = s_pts[(size_t)ind * 3 + 1] - qy;
    const float pz = s_pts[(size_t)ind * 3 + 2] - qz;
    float best = 1e30f; int bk = 0;
    #pragma unroll
    for (int k = 0; k < 15; ++k) {        // kpts -> uniform SGPR loads
        float ex = px - kpts[k * 3 + 0];
        float ey = py - kpts[k * 3 + 1];
        float ez = pz - kpts[k * 3 + 2];
        float d2 = fmaf(ex, ex, fmaf(ey, ey, ez * ez));
        if (d2 < best) { best = d2; bk = k; }   // strict < = first-min (argmin rule)
    }
    const float infl = fmaxf(0.f, 1.f - sqrtf(best));   // SIGMA = 1

    __syncthreads();   // mod_lds + wt_lds ready

    // ---------------- consume ----------------
    float acc[2][8];
    #pragma unroll
    for (int qq = 0; qq < 2; ++qq)
        #pragma unroll
        for (int e = 0; e < 8; ++e) acc[qq][e] = 0.f;

    #pragma unroll
    for (int qq = 0; qq < 2; ++qq) {
        const int row = pb * 2 + qq;
        #pragma unroll
        for (int cc = 0; cc < 4; ++cc) {
            const int idx = qq * 32 + cc * 8 + hl;
            const int kh  = __shfl(bk, idx);
            const float fl = __shfl(infl, idx);
            const float sv = mod_lds[row * 120 + kh * 8 + cdiv];
            const float w  = sv * fl;
            const float4 wa = *(const float4*)&wt_lds[kh * 64 + cdiv * 8];
            const float4 wb = *(const float4*)&wt_lds[kh * 64 + cdiv * 8 + 4];
            const bf16x8 f8 = fv[qq][cc];
            acc[qq][0] = fmaf(bf2f((u16)f8[0]), wa.x * w, acc[qq][0]);
            acc[qq][1] = fmaf(bf2f((u16)f8[1]), wa.y * w, acc[qq][1]);
            acc[qq][2] = fmaf(bf2f((u16)f8[2]), wa.z * w, acc[qq][2]);
            acc[qq][3] = fmaf(bf2f((u16)f8[3]), wa.w * w, acc[qq][3]);
            acc[qq][4] = fmaf(bf2f((u16)f8[4]), wb.x * w, acc[qq][4]);
            acc[qq][5] = fmaf(bf2f((u16)f8[5]), wb.y * w, acc[qq][5]);
            acc[qq][6] = fmaf(bf2f((u16)f8[6]), wb.z * w, acc[qq][6]);
            acc[qq][7] = fmaf(bf2f((u16)f8[7]), wb.w * w, acc[qq][7]);
        }
    }

    // butterfly reduce over hl (lane bits 3..5)
    #pragma unroll
    for (int step = 8; step <= 32; step <<= 1)
        #pragma unroll
        for (int qq = 0; qq < 2; ++qq)
            #pragma unroll
            for (int e = 0; e < 8; ++e)
                acc[qq][e] += __shfl_xor(acc[qq][e], step);

    if (hl == 0) {
        #pragma unroll
        for (int qq = 0; qq < 2; ++qq) {
            f32x4 o0 = {acc[qq][0], acc[qq][1], acc[qq][2], acc[qq][3]};
            f32x4 o1 = {acc[qq][4], acc[qq][5], acc[qq][6], acc[qq][7]};
            float* dst = out + (size_t)(m0p + qq) * 64 + cdiv * 8;
            __builtin_nontemporal_store(o0, (f32x4*)dst);
            __builtin_nontemporal_store(o1, (f32x4*)(dst + 4));
        }
    }
}

// ------------------- fallback tier: proven f32 path -------------------
__global__ __launch_bounds__(256, 3)
void mod_mlp(const float* __restrict__ s_feats,
             const float* __restrict__ w1,
             const float* __restrict__ b1,
             const float* __restrict__ w2,
             float* __restrict__ modw)
{
    __shared__ float w1_lds[64 * 64];
    __shared__ float w2_lds[64 * 120 + 8];

    const int tid = threadIdx.x;
    {
        const float4* s1 = (const float4*)w1;
        float4* d1 = (float4*)w1_lds;
        #pragma unroll
        for (int i = 0; i < 4; ++i) d1[tid + 256 * i] = s1[tid + 256 * i];
        const float4* s2 = (const float4*)w2;
        float4* d2 = (float4*)w2_lds;
        for (int i = tid; i < (64 * 120) / 4; i += 256) d2[i] = s2[i];
        if (tid < 8) w2_lds[64 * 120 + tid] = 0.f;
    }
    __syncthreads();

    const int lane = tid & 63;
    const int wid  = tid >> 6;
    const int c    = lane;
    const int nwaves = gridDim.x * 4;
    const int gwave  = blockIdx.x * 4 + wid;
    const float b1v = b1[c];
    const int cB = 64 + ((c < 56) ? c : 55);

    for (int pair = gwave; pair * 2 < MQ; pair += nwaves) {
        const int m0 = pair * 2;
        float f0 = s_feats[(size_t)m0 * 64 + c];
        float f1 = s_feats[(size_t)(m0 + 1) * 64 + c];
        float h0a = b1v, h0b = 0.f, h1a = b1v, h1b = 0.f;
        #pragma unroll
        for (int i = 0; i < 64; i += 2) {
            float wa = w1_lds[i * 64 + c];
            float wb = w1_lds[(i + 1) * 64 + c];
            h0a = fmaf(rlf(f0, i), wa, h0a);
            h0b = fmaf(rlf(f0, i + 1), wb, h0b);
            h1a = fmaf(rlf(f1, i), wa, h1a);
            h1b = fmaf(rlf(f1, i + 1), wb, h1b);
        }
        float h0 = h0a + h0b, h1 = h1a + h1b;
        h0 = (h0 >= 0.f) ? h0 : 0.1f * h0;
        h1 = (h1 >= 0.f) ? h1 : 0.1f * h1;
        float a00 = 0.f, a01 = 0.f, a10 = 0.f, a11 = 0.f;
        #pragma unroll
        for (int i = 0; i < 64; ++i) {
            float wA = w2_lds[i * 120 + c];
            float wB = w2_lds[i * 120 + cB];
            float s0 = rlf(h0, i);
            float s1 = rlf(h1, i);
            a00 = fmaf(s0, wA, a00);
            a01 = fmaf(s0, wB, a01);
            a10 = fmaf(s1, wA, a10);
            a11 = fmaf(s1, wB, a11);
        }
        modw[(size_t)m0 * 120 + c]       = 1.f / (1.f + __expf(-a00));
        modw[(size_t)(m0 + 1) * 120 + c] = 1.f / (1.f + __expf(-a10));
        if (c < 56) {
            modw[(size_t)m0 * 120 + 64 + c]       = 1.f / (1.f + __expf(-a01));
            modw[(size_t)(m0 + 1) * 120 + 64 + c] = 1.f / (1.f + __expf(-a11));
        }
    }
}

__global__ __launch_bounds__(256, 4)
void kp_gather(const float* __restrict__ q_pts,
               const float* __restrict__ s_pts,
               const float* __restrict__ s_feats,
               const int*   __restrict__ neighb_inds,
               const float* __restrict__ kpts,
               const float* __restrict__ weights,
               const float* __restrict__ modw,
               float* __restrict__ out)
{
    __shared__ float wt_lds[15 * 64];
    const int tid = threadIdx.x;
    if (tid < 240) ((float4*)wt_lds)[tid] = ((const float4*)weights)[tid];
    __syncthreads();

    const int lane = tid & 63;
    const int wid  = tid >> 6;
    const int c    = lane;
    const int u    = c >> 3;
    const int pair = blockIdx.x * 4 + wid;
    const int m0 = pair * 2;

    const int q = lane >> 5;
    const int m = m0 + q;
    const int ind = neighb_inds[(size_t)m0 * 32 + lane];
    const float qx = q_pts[m * 3 + 0];
    const float qy = q_pts[m * 3 + 1];
    const float qz = q_pts[m * 3 + 2];
    const float px = s_pts[(size_t)ind * 3 + 0] - qx;
    const float py = s_pts[(size_t)ind * 3 + 1] - qy;
    const float pz = s_pts[(size_t)ind * 3 + 2] - qz;
    float best = 1e30f; int bk = 0;
    #pragma unroll
    for (int k = 0; k < 15; ++k) {
        float ex = px - kpts[k * 3 + 0];
        float ey = py - kpts[k * 3 + 1];
        float ez = pz - kpts[k * 3 + 2];
        float d2 = fmaf(ex, ex, fmaf(ey, ey, ez * ez));
        if (d2 < best) { best = d2; bk = k; }
    }
    const float infl = fmaxf(0.f, 1.f - sqrtf(best));
    const int pk = (ind << 4) | bk;

    const size_t mb0 = (size_t)m0 * 120, mb1 = mb0 + 120;
    const float vA0 = modw[mb0 + c];
    const float vB0 = (c < 56) ? modw[mb0 + 64 + c] : 0.f;
    const float vA1 = modw[mb1 + c];
    const float vB1 = (c < 56) ? modw[mb1 + 64 + c] : 0.f;

    float fv0[32], fv1[32];
    #pragma unroll
    for (int h = 0; h < 32; ++h)
        fv0[h] = s_feats[(size_t)(rli(pk, h) >> 4) * 64 + c];
    #pragma unroll
    for (int h = 0; h < 32; ++h)
        fv1[h] = s_feats[(size_t)(rli(pk, 32 + h) >> 4) * 64 + c];

    float p0 = 0.f, p1 = 0.f, p2 = 0.f, p3 = 0.f;
    #pragma unroll
    for (int h = 0; h < 32; h += 4) {
        #pragma unroll
        for (int j = 0; j < 4; ++j) {
            const int s = rli(pk, h + j);
            const int kh = s & 15;
            const float fl = rlf(infl, h + j);
            const float sv = (kh < 8) ? __shfl(vA0, (kh << 3) + u)
                                      : __shfl(vB0, ((kh - 8) << 3) + u);
            const float w = wt_lds[(kh << 6) + c] * sv * fl;
            float& p = (j == 0) ? p0 : (j == 1) ? p1 : (j == 2) ? p2 : p3;
            p = fmaf(fv0[h + j], w, p);
        }
    }
    const float acc0 = (p0 + p1) + (p2 + p3);

    float r0 = 0.f, r1 = 0.f, r2 = 0.f, r3 = 0.f;
    #pragma unroll
    for (int h = 0; h < 32; h += 4) {
        #pragma unroll
        for (int j = 0; j < 4; ++j) {
            const int s = rli(pk, 32 + h + j);
            const int kh = s & 15;
            const float fl = rlf(infl, 32 + h + j);
            const float sv = (kh < 8) ? __shfl(vA1, (kh << 3) + u)
                                      : __shfl(vB1, ((kh - 8) << 3) + u);
            const float w = wt_lds[(kh << 6) + c] * sv * fl;
            float& p = (j == 0) ? r0 : (j == 1) ? r1 : (j == 2) ? r2 : r3;
            p = fmaf(fv1[h + j], w, p);
        }
    }
    const float acc1 = (r0 + r1) + (r2 + r3);

    out[(size_t)m0 * 64 + c]       = acc0;
    out[(size_t)(m0 + 1) * 64 + c] = acc1;
}

extern "C" void kernel_launch(void* const* d_in, const int* in_sizes, int n_in,
                              void* d_out, int out_size, void* d_ws, size_t ws_size,
                              hipStream_t stream) {
    const float* q_pts       = (const float*)d_in[0];
    const float* s_pts       = (const float*)d_in[1];
    const float* s_feats     = (const float*)d_in[2];
    const int*   neighb_inds = (const int*)d_in[3];
    const float* kpts        = (const float*)d_in[4];
    const float* weights     = (const float*)d_in[5];
    const float* w1          = (const float*)d_in[6];
    const float* b1          = (const float*)d_in[7];
    const float* w2          = (const float*)d_in[8];
    float* out = (float*)d_out;

    // ws layout: fb 4.096MB | w1p 8KB | w2p 16KB
    const size_t offFB  = 0;
    const size_t offW1P = (size_t)MQ * 64 * sizeof(u16);     // 4,096,000
    const size_t offW2P = offW1P + 4096 * sizeof(u16);
    const size_t needBF = offW2P + 8192 * sizeof(u16);       // ~4.12 MB
    const size_t needF32 = (size_t)MQ * 120 * sizeof(float); // 15.36 MB

    if (ws_size >= needBF) {
        u16* fb  = (u16*)((char*)d_ws + offFB);
        u16* w1p = (u16*)((char*)d_ws + offW1P);
        u16* w2p = (u16*)((char*)d_ws + offW2P);
        fb_build<<<512, 256, 0, stream>>>(s_feats, w1, w2, fb, w1p, w2p);
        kp_fused<<<MQ / 16, 512, 0, stream>>>(q_pts, s_pts, fb, neighb_inds,
                                              kpts, weights, w1p, b1, w2p, out);
    } else if (ws_size >= needF32) {
        float* modw = (float*)d_ws;
        mod_mlp<<<768, 256, 0, stream>>>(s_feats, w1, b1, w2, modw);
        kp_gather<<<MQ / 8, 256, 0, stream>>>(q_pts, s_pts, s_feats, neighb_inds,
                                              kpts, weights, modw, out);
    }
}